// Round 3
// baseline (2016.044 us; speedup 1.0000x reference)
//
#include <hip/hip_runtime.h>
#include <math.h>

// DP-means on MI355X — single persistent kernel with device-wide barrier.
// R3: kill the latency-bound serial loops (init colsum, phase D segment sum)
// via batched loads (16 in flight) + ds_add_f32 LDS atomics (no RMW chain).
// Phase A (assign GEMM) arithmetic is unchanged from the validated version.

#define NPTS   65536
#define DDIM   1024
#define KMAX   64
#define GRID   256
#define LAMBDA_F 1000.0f
#define INF_F  1e30f

struct Scal {
  int K, it, done, _p;
  double prev_obj;
  double s_all[2], s_far[2], sx2far[2];
  int farcnt[2];
  int counts[2][64];
};

// sense-reversal grid barrier, device (agent) scope.
// Safe: grid == 256 blocks == #CUs, 64 KB LDS/block -> all blocks co-resident.
__device__ __forceinline__ void gbar(int* cnt, int* gen) {
  __syncthreads();
  if (threadIdx.x == 0) {
    __threadfence();
    int g = __hip_atomic_load(gen, __ATOMIC_RELAXED, __HIP_MEMORY_SCOPE_AGENT);
    int a = __hip_atomic_fetch_add(cnt, 1, __ATOMIC_ACQ_REL, __HIP_MEMORY_SCOPE_AGENT);
    if (a == GRID - 1) {
      __hip_atomic_store(cnt, 0, __ATOMIC_RELAXED, __HIP_MEMORY_SCOPE_AGENT);
      __hip_atomic_store(gen, g + 1, __ATOMIC_RELEASE, __HIP_MEMORY_SCOPE_AGENT);
    } else {
      while (__hip_atomic_load(gen, __ATOMIC_ACQUIRE, __HIP_MEMORY_SCOPE_AGENT) == g)
        __builtin_amdgcn_s_sleep(1);
    }
    __threadfence();
  }
  __syncthreads();
}

__global__ void kInit(int* bar) { bar[threadIdx.x] = 0; }

__global__ __launch_bounds__(256, 1) void kMain(
    const float* __restrict__ X, float* __restrict__ mu,
    float* __restrict__ x2, int* __restrict__ z,
    double* __restrict__ sums, double* __restrict__ musum,
    float* __restrict__ m2f, Scal* sc, int* bar) {
  __shared__ __align__(16) char smem[65536];
  const int tid = threadIdx.x;
  const int b = blockIdx.x;
  const int lane = tid & 63, wv = tid >> 6;
  int* bcnt = bar;
  int* bgen = bar + 32;

  // ---- I0: zero persistent state ----
  sums[(b << 8) + tid] = 0.0;
  if (b == 0) {
    if (tid < 64) { sc->counts[0][tid] = 0; sc->counts[1][tid] = 0; }
    if (tid == 0) {
      sc->K = 1; sc->it = 0; sc->done = 0; sc->prev_obj = 0.0;
      for (int s2 = 0; s2 < 2; ++s2) {
        sc->s_all[s2] = 0.0; sc->s_far[s2] = 0.0; sc->sx2far[s2] = 0.0; sc->farcnt[s2] = 0;
      }
    }
  }
  if (b == 1) {
    musum[tid] = 0.0; musum[256 + tid] = 0.0;
    musum[512 + tid] = 0.0; musum[768 + tid] = 0.0;
  }
  gbar(bcnt, bgen);

  // ---- I1: x2 per point (wave-per-point, batched 4) + column sums for mu0 ----
  {
    const int pbase = b << 8;
    for (int i0 = 0; i0 < 64; i0 += 4) {
      float4 v[4][4];
      #pragma unroll
      for (int u = 0; u < 4; ++u) {
        const int p = pbase + ((i0 + u) << 2) + wv;
        const float* row = X + ((size_t)p << 10);
        #pragma unroll
        for (int c = 0; c < 4; ++c)
          v[u][c] = *(const float4*)&row[(c << 8) + (lane << 2)];
      }
      #pragma unroll
      for (int u = 0; u < 4; ++u) {
        float s = 0.f;
        #pragma unroll
        for (int c = 0; c < 4; ++c)
          s += v[u][c].x * v[u][c].x + v[u][c].y * v[u][c].y +
               v[u][c].z * v[u][c].z + v[u][c].w * v[u][c].w;
        #pragma unroll
        for (int m = 1; m < 64; m <<= 1) s += __shfl_xor(s, m);
        if (lane == 0) x2[pbase + ((i0 + u) << 2) + wv] = s;
      }
    }
    // column sums: block owns points [b*256, b*256+256), thread owns 4 dims
    // (float4, coalesced); ordered per-column fp32 accumulation, fp64 merge.
    const float* xb = X + ((size_t)(b << 8) << 10) + (tid << 2);
    float4 a = make_float4(0.f, 0.f, 0.f, 0.f);
    for (int p0 = 0; p0 < 256; p0 += 8) {
      float4 t[8];
      #pragma unroll
      for (int u = 0; u < 8; ++u) t[u] = *(const float4*)&xb[(size_t)(p0 + u) << 10];
      #pragma unroll
      for (int u = 0; u < 8; ++u) {
        a.x += t[u].x; a.y += t[u].y; a.z += t[u].z; a.w += t[u].w;
      }
    }
    unsafeAtomicAdd(&musum[(tid << 2) + 0], (double)a.x);
    unsafeAtomicAdd(&musum[(tid << 2) + 1], (double)a.y);
    unsafeAtomicAdd(&musum[(tid << 2) + 2], (double)a.z);
    unsafeAtomicAdd(&musum[(tid << 2) + 3], (double)a.w);
  }
  gbar(bcnt, bgen);

  // ---- I2: mu[0]=mean, mu[k>0]=0, m2 ----
  if (b < KMAX) {
    double* w = (double*)smem;
    const int k = b;
    if (k == 0) {
      double ss = 0.0;
      #pragma unroll
      for (int r = 0; r < 4; ++r) {
        int d = (r << 8) + tid;
        float m = (float)(musum[d] * (1.0 / 65536.0));
        mu[d] = m;
        ss += (double)m * (double)m;
      }
      #pragma unroll
      for (int mk = 1; mk < 64; mk <<= 1) ss += __shfl_xor(ss, mk);
      if (lane == 0) w[wv] = ss;
      __syncthreads();
      if (tid == 0) m2f[0] = (float)(w[0] + w[1] + w[2] + w[3]);
    } else {
      #pragma unroll
      for (int r = 0; r < 4; ++r) mu[(k << 10) + (r << 8) + tid] = 0.f;
      if (tid == 0) m2f[k] = 0.f;
    }
  }
  gbar(bcnt, bgen);

  // ---- main loop: break on convergence (freeze semantics) ----
  for (int t = 0; t < 50; ++t) {
    const int dn = *(volatile int*)&sc->done;
    if (dn) break;
    const int K = *(volatile int*)&sc->K;
    const int Kc = (K < KMAX - 1) ? K : (KMAX - 1);
    const int slot = t & 1;

    // ---- Phase A: assign (dist GEMM) + final z + counts + obj partials ----
    {
      constexpr int LSTR = 34;
      float*  lX   = (float*)smem;             // 34816 B
      float*  lMu  = (float*)(smem + 34816);   //  8704 B
      double* wred = (double*)(smem + 43520);  //    96 B
      int*    wfc  = (int*)(smem + 43616);     //    16 B
      int*    lcnt = (int*)(smem + 43648);     //   256 B
      const int pg = tid & 31, kg = tid >> 5;
      const int pbase = b << 8;
      const bool kact = (kg << 3) < K;
      if (tid < KMAX) lcnt[tid] = 0;

      float acc[8][8];
      #pragma unroll
      for (int i = 0; i < 8; ++i)
        #pragma unroll
        for (int j = 0; j < 8; ++j) acc[i][j] = 0.f;

      for (int dc = 0; dc < DDIM; dc += 32) {
        #pragma unroll
        for (int r = 0; r < 16; ++r) {
          int idx = (r << 8) + tid;
          int p = idx >> 4, c2 = (idx & 15) << 1;
          *(float2*)&lX[p * LSTR + c2] =
              *(const float2*)&X[((size_t)(pbase + p) << 10) + dc + c2];
        }
        #pragma unroll
        for (int r = 0; r < 4; ++r) {
          int idx = (r << 8) + tid;
          int k = idx >> 4, c2 = (idx & 15) << 1;
          *(float2*)&lMu[k * LSTR + c2] = *(const float2*)&mu[(k << 10) + dc + c2];
        }
        __syncthreads();
        if (kact) {
          for (int d2 = 0; d2 < 16; ++d2) {
            float2 xa[8], ma[8];
            #pragma unroll
            for (int j = 0; j < 8; ++j)
              ma[j] = *(const float2*)&lMu[((kg << 3) + j) * LSTR + (d2 << 1)];
            #pragma unroll
            for (int i = 0; i < 8; ++i)
              xa[i] = *(const float2*)&lX[((i << 5) + pg) * LSTR + (d2 << 1)];
            #pragma unroll
            for (int i = 0; i < 8; ++i)
              #pragma unroll
              for (int j = 0; j < 8; ++j)
                acc[i][j] = fmaf(xa[i].y, ma[j].y, fmaf(xa[i].x, ma[j].x, acc[i][j]));
          }
        }
        __syncthreads();
      }

      float x2v[8];
      #pragma unroll
      for (int i = 0; i < 8; ++i) x2v[i] = x2[pbase + (i << 5) + pg];
      float m2v[8];
      #pragma unroll
      for (int j = 0; j < 8; ++j) m2v[j] = kact ? m2f[(kg << 3) + j] : 0.f;

      float* rd = lX;
      int*   rk = (int*)(lX + 2048);
      #pragma unroll
      for (int i = 0; i < 8; ++i) {
        float bd2 = INF_F; int bk2 = KMAX;
        if (kact) {
          #pragma unroll
          for (int j = 0; j < 8; ++j) {
            int k = (kg << 3) + j;
            if (k < K) {
              float dist = x2v[i] - 2.0f * acc[i][j] + m2v[j];
              if (dist < bd2) { bd2 = dist; bk2 = k; }
            }
          }
        }
        rd[(tid << 3) + i] = bd2;
        rk[(tid << 3) + i] = bk2;
      }
      __syncthreads();
      const int ii = tid >> 5, ppg = tid & 31;
      float bd = INF_F; int bk = KMAX;
      #pragma unroll
      for (int g = 0; g < 8; ++g) {
        int src = (((g << 5) + ppg) << 3) + ii;
        float dv = rd[src]; int kv = rk[src];
        if (dv < bd || (dv == bd && kv < bk)) { bd = dv; bk = kv; }
      }
      const bool far = bd > LAMBDA_F;
      const int zf = (far && (K < KMAX)) ? Kc : bk;
      z[pbase + tid] = zf;
      atomicAdd(&lcnt[zf], 1);

      const float x2p = x2[pbase + tid];
      double a = (double)bd;
      double f = far ? (double)bd : 0.0;
      double xf = far ? (double)x2p : 0.0;
      unsigned long long bal = __ballot(far);
      int fc = __popcll(bal);
      #pragma unroll
      for (int m = 1; m < 64; m <<= 1) {
        a += __shfl_xor(a, m); f += __shfl_xor(f, m); xf += __shfl_xor(xf, m);
      }
      if (lane == 0) { wred[wv] = a; wred[4 + wv] = f; wred[8 + wv] = xf; wfc[wv] = fc; }
      __syncthreads();
      if (tid == 0) {
        unsafeAtomicAdd(&sc->s_all[slot],  wred[0] + wred[1] + wred[2] + wred[3]);
        unsafeAtomicAdd(&sc->s_far[slot],  wred[4] + wred[5] + wred[6] + wred[7]);
        unsafeAtomicAdd(&sc->sx2far[slot], wred[8] + wred[9] + wred[10] + wred[11]);
        atomicAdd(&sc->farcnt[slot], wfc[0] + wfc[1] + wfc[2] + wfc[3]);
      }
      if (tid < KMAX) {
        int c = lcnt[tid];
        if (c > 0) atomicAdd(&sc->counts[slot][tid], c);
      }
    }
    gbar(bcnt, bgen);

    // ---- Phase D: segment sums — batched loads + ds_add_f32 (no RMW chain) ----
    {
      float (*accS)[256] = (float (*)[256])(void*)smem;  // 64 KB
      const int dcb = b & 3, nb = b >> 2;
      const int p0 = nb << 10;
      #pragma unroll
      for (int k = 0; k < KMAX; ++k) accS[k][tid] = 0.f;
      __syncthreads();
      const float* xp = X + ((size_t)p0 << 10) + (dcb << 8) + tid;
      const int* zp = z + p0;
      for (int pb = 0; pb < 1024; pb += 16) {
        float v[16]; int zi[16];
        #pragma unroll
        for (int u = 0; u < 16; ++u) v[u] = xp[(size_t)(pb + u) << 10];
        #pragma unroll
        for (int u = 0; u < 16; ++u) zi[u] = zp[pb + u];
        #pragma unroll
        for (int u = 0; u < 16; ++u) atomicAdd(&accS[zi[u]][tid], v[u]);
      }
      __syncthreads();
      for (int k = 0; k < KMAX; ++k)
        if (sc->counts[slot][k] > 0)
          unsafeAtomicAdd(&sums[(k << 10) + (dcb << 8) + tid], (double)accS[k][tid]);
    }
    gbar(bcnt, bgen);

    // ---- Phase E: centroid means + m2; block Kc also does obj/convergence ----
    if (b < KMAX) {
      double* w = (double*)smem;
      const int k = b;
      const int c = sc->counts[slot][k];
      const double inv = (c > 0) ? 1.0 / (double)c : 0.0;
      double ss = 0.0;
      #pragma unroll
      for (int r = 0; r < 4; ++r) {
        int d = (r << 8) + tid;
        float m = mu[(k << 10) + d];
        if (c > 0) m = (float)(sums[(k << 10) + d] * inv);
        mu[(k << 10) + d] = m;
        sums[(k << 10) + d] = 0.0;
        ss += (double)m * (double)m;
      }
      #pragma unroll
      for (int mk = 1; mk < 64; mk <<= 1) ss += __shfl_xor(ss, mk);
      if (lane == 0) w[wv] = ss;
      __syncthreads();
      float m2k = 0.f;
      if (tid == 0) {
        m2k = (float)(w[0] + w[1] + w[2] + w[3]);
        m2f[k] = m2k;
      }
      if (k == Kc) {
        if (tid < 64) sc->counts[slot ^ 1][tid] = 0;
        if (tid == 0) {
          sc->s_all[slot ^ 1] = 0.0; sc->s_far[slot ^ 1] = 0.0;
          sc->sx2far[slot ^ 1] = 0.0; sc->farcnt[slot ^ 1] = 0;
          int farc = sc->farcnt[slot];
          int create = (farc > 0 && K < KMAX) ? 1 : 0;
          int Knew = K + create;
          double obj;
          if (create)
            obj = (sc->s_all[slot] - sc->s_far[slot]) +
                  (sc->sx2far[slot] - (double)farc * (double)m2k);
          else
            obj = sc->s_all[slot];
          obj += 1000.0 * (double)Knew;
          int conv = (sc->it > 0) && (fabs(obj - sc->prev_obj) < 1e-3 * obj);
          sc->done = conv;
          sc->prev_obj = obj;
          sc->K = Knew;
          sc->it = sc->it + 1;
        }
      }
    }
    gbar(bcnt, bgen);
  }
}

// ---------------- host ----------------

extern "C" void kernel_launch(void* const* d_in, const int* in_sizes, int n_in,
                              void* d_out, int out_size, void* d_ws, size_t ws_size,
                              hipStream_t stream) {
  const float* X = (const float*)d_in[0];
  float* mu = (float*)d_out;                   // 64 x 1024 fp32 output
  char* ws = (char*)d_ws;
  float*  x2    = (float*)(ws + 0);            // 256 KB
  int*    z     = (int*)(ws + 262144);         // 256 KB
  double* sums  = (double*)(ws + 524288);      // 512 KB
  double* musum = (double*)(ws + 1048576);     // 8 KB
  float*  m2f   = (float*)(ws + 1056768);      // 256 B
  Scal*   sc    = (Scal*)(ws + 1057024);       // ~600 B
  int*    bar   = (int*)(ws + 1058048);        // 256 B

  kInit<<<1, 64, 0, stream>>>(bar);
  kMain<<<GRID, 256, 0, stream>>>(X, mu, x2, z, sums, musum, m2f, sc, bar);
}

// Round 4
// 1675.519 us; speedup vs baseline: 1.2032x; 1.2032x over previous
//
#include <hip/hip_runtime.h>
#include <math.h>

// DP-means on MI355X. R4: fix the occupancy bottleneck (was 4 waves/CU).
//  - init (x2 + colsum fused, ONE X pass) as a regular 2048-block kernel
//  - persistent loop: 256 blocks x 1024 threads = 16 waves/CU (VGPR<=128)
//  - phase D shares phase A's point partition (z in LDS) -> 2 barriers/iter
// Boundary-sensitive arithmetic kept op-identical to the passing version.

#define NPTS   65536
#define DDIM   1024
#define KMAX   64
#define GRID   256
#define LAMBDA_F 1000.0f
#define INF_F  1e30f

struct Scal {
  int K, it, done, _p;
  double prev_obj;
  double s_all[2], s_far[2], sx2far[2];
  int farcnt[2];
  int counts[2][64];
};

// sense-reversal grid barrier, device (agent) scope.
// Safe: 256 blocks, 1024 thr + 65 KB LDS -> exactly 1 block/CU, all co-resident.
__device__ __forceinline__ void gbar(int* cnt, int* gen) {
  __syncthreads();
  if (threadIdx.x == 0) {
    __threadfence();
    int g = __hip_atomic_load(gen, __ATOMIC_RELAXED, __HIP_MEMORY_SCOPE_AGENT);
    int a = __hip_atomic_fetch_add(cnt, 1, __ATOMIC_ACQ_REL, __HIP_MEMORY_SCOPE_AGENT);
    if (a == GRID - 1) {
      __hip_atomic_store(cnt, 0, __ATOMIC_RELAXED, __HIP_MEMORY_SCOPE_AGENT);
      __hip_atomic_store(gen, g + 1, __ATOMIC_RELEASE, __HIP_MEMORY_SCOPE_AGENT);
    } else {
      while (__hip_atomic_load(gen, __ATOMIC_ACQUIRE, __HIP_MEMORY_SCOPE_AGENT) == g)
        __builtin_amdgcn_s_sleep(2);
    }
    __threadfence();
  }
  __syncthreads();
}

// ---- init: x2 per point + column sums, ONE pass over X. 2048 blocks x 256. ----
__global__ __launch_bounds__(256) void kInitF(const float* __restrict__ X,
                                              float* __restrict__ x2,
                                              double* __restrict__ musum) {
  __shared__ float colpart[4][1024];   // per-wave column partials (16 KB)
  const int tid = threadIdx.x, lane = tid & 63, wv = tid >> 6;
  const int pbase = blockIdx.x << 5;   // 32 points per block, 8 per wave
  float4 cs[4];
  #pragma unroll
  for (int c = 0; c < 4; ++c) cs[c] = make_float4(0.f, 0.f, 0.f, 0.f);

  for (int i0 = 0; i0 < 8; i0 += 2) {
    float4 v[2][4];
    #pragma unroll
    for (int u = 0; u < 2; ++u) {
      const int p = pbase + (wv << 3) + i0 + u;
      const float* row = X + ((size_t)p << 10);
      #pragma unroll
      for (int c = 0; c < 4; ++c)
        v[u][c] = *(const float4*)&row[(c << 8) + (lane << 2)];
    }
    #pragma unroll
    for (int u = 0; u < 2; ++u) {
      float s = 0.f;
      #pragma unroll
      for (int c = 0; c < 4; ++c)
        s += v[u][c].x * v[u][c].x + v[u][c].y * v[u][c].y +
             v[u][c].z * v[u][c].z + v[u][c].w * v[u][c].w;
      #pragma unroll
      for (int m = 1; m < 64; m <<= 1) s += __shfl_xor(s, m);
      if (lane == 0) x2[pbase + (wv << 3) + i0 + u] = s;
      #pragma unroll
      for (int c = 0; c < 4; ++c) {
        cs[c].x += v[u][c].x; cs[c].y += v[u][c].y;
        cs[c].z += v[u][c].z; cs[c].w += v[u][c].w;
      }
    }
  }
  #pragma unroll
  for (int c = 0; c < 4; ++c)
    *(float4*)&colpart[wv][(c << 8) + (lane << 2)] = cs[c];
  __syncthreads();
  // thread owns 4 dims; deterministic wave order 0..3
  float4 r0 = *(const float4*)&colpart[0][tid << 2];
  float4 r1 = *(const float4*)&colpart[1][tid << 2];
  float4 r2 = *(const float4*)&colpart[2][tid << 2];
  float4 r3 = *(const float4*)&colpart[3][tid << 2];
  float sx = ((r0.x + r1.x) + r2.x) + r3.x;
  float sy = ((r0.y + r1.y) + r2.y) + r3.y;
  float sz = ((r0.z + r1.z) + r2.z) + r3.z;
  float sw = ((r0.w + r1.w) + r2.w) + r3.w;
  unsafeAtomicAdd(&musum[(tid << 2) + 0], (double)sx);
  unsafeAtomicAdd(&musum[(tid << 2) + 1], (double)sy);
  unsafeAtomicAdd(&musum[(tid << 2) + 2], (double)sz);
  unsafeAtomicAdd(&musum[(tid << 2) + 3], (double)sw);
}

// ---- mu0 finalize: mu[0]=mean, mu[k>0]=0, m2; also sc->K=1 ----
__global__ __launch_bounds__(256) void kMu0(const double* __restrict__ musum,
                                            float* __restrict__ mu,
                                            float* __restrict__ m2f, Scal* sc) {
  __shared__ double w[4];
  const int k = blockIdx.x, tid = threadIdx.x;
  const int lane = tid & 63, wv = tid >> 6;
  if (k == 0) {
    double ss = 0.0;
    #pragma unroll
    for (int r = 0; r < 4; ++r) {
      int d = (r << 8) + tid;
      float m = (float)(musum[d] * (1.0 / 65536.0));
      mu[d] = m;
      ss += (double)m * (double)m;
    }
    #pragma unroll
    for (int mk = 1; mk < 64; mk <<= 1) ss += __shfl_xor(ss, mk);
    if (lane == 0) w[wv] = ss;
    __syncthreads();
    if (tid == 0) { m2f[0] = (float)(w[0] + w[1] + w[2] + w[3]); sc->K = 1; }
  } else {
    #pragma unroll
    for (int r = 0; r < 4; ++r) mu[(k << 10) + (r << 8) + tid] = 0.f;
    if (tid == 0) m2f[k] = 0.f;
  }
}

// ---- persistent loop: 256 blocks x 1024 threads ----
__global__ __launch_bounds__(1024) void kLoop(
    const float* __restrict__ X, float* __restrict__ mu,
    const float* __restrict__ x2, double* __restrict__ sums,
    float* __restrict__ m2f, Scal* sc, int* bar) {
  __shared__ __align__(16) float smem[16384];  // 64 KB union (lX/lMu | rd/rk | accS | w)
  __shared__ int zL[256];
  __shared__ int lcnt[64];
  __shared__ double wred[12];
  __shared__ int wfc[4];
  const int tid = threadIdx.x;
  const int b = blockIdx.x;
  const int pbase = b << 8;
  int* bcnt = bar;
  int* bgen = bar + 32;

  for (int t = 0; t < 50; ++t) {
    if (*(volatile int*)&sc->done) break;
    const int K = *(volatile int*)&sc->K;
    const int Kc = (K < KMAX - 1) ? K : (KMAX - 1);
    const int slot = t & 1;

    // ---- Phase A: dist GEMM (256 pts x 64 slots; thread = 2 pts x 8 slots) ----
    {
      float* lX  = smem;          // 256*34 = 8704 floats
      float* lMu = smem + 8704;   // 64*34  = 2176 floats
      const int pg = tid & 127, kg = tid >> 7;
      const bool kact = (kg << 3) < K;
      if (tid < 64) lcnt[tid] = 0;

      float acc[2][8];
      #pragma unroll
      for (int i = 0; i < 2; ++i)
        #pragma unroll
        for (int j = 0; j < 8; ++j) acc[i][j] = 0.f;

      for (int dc = 0; dc < DDIM; dc += 32) {
        #pragma unroll
        for (int r = 0; r < 4; ++r) {
          int idx = (r << 10) + tid;
          int p = idx >> 4, c2 = (idx & 15) << 1;
          *(float2*)&lX[p * 34 + c2] =
              *(const float2*)&X[((size_t)(pbase + p) << 10) + dc + c2];
        }
        {
          int k = tid >> 4, c2 = (tid & 15) << 1;
          *(float2*)&lMu[k * 34 + c2] = *(const float2*)&mu[(k << 10) + dc + c2];
        }
        __syncthreads();
        if (kact) {
          for (int d2 = 0; d2 < 16; ++d2) {
            float2 ma[8], xa[2];
            #pragma unroll
            for (int j = 0; j < 8; ++j)
              ma[j] = *(const float2*)&lMu[((kg << 3) + j) * 34 + (d2 << 1)];
            #pragma unroll
            for (int i = 0; i < 2; ++i)
              xa[i] = *(const float2*)&lX[((i << 7) + pg) * 34 + (d2 << 1)];
            #pragma unroll
            for (int i = 0; i < 2; ++i)
              #pragma unroll
              for (int j = 0; j < 8; ++j)
                acc[i][j] = fmaf(xa[i].y, ma[j].y, fmaf(xa[i].x, ma[j].x, acc[i][j]));
          }
        }
        __syncthreads();
      }

      float x2v[2];
      #pragma unroll
      for (int i = 0; i < 2; ++i) x2v[i] = x2[pbase + (i << 7) + pg];
      float m2v[8];
      #pragma unroll
      for (int j = 0; j < 8; ++j) m2v[j] = kact ? m2f[(kg << 3) + j] : 0.f;

      float* rd = smem;                 // 2048 floats (overlay lX; GEMM done)
      int*   rk = (int*)(smem + 2048);  // 2048 ints
      #pragma unroll
      for (int i = 0; i < 2; ++i) {
        float bd2 = INF_F; int bk2 = KMAX;
        if (kact) {
          #pragma unroll
          for (int j = 0; j < 8; ++j) {
            int k = (kg << 3) + j;
            if (k < K) {
              float dist = x2v[i] - 2.0f * acc[i][j] + m2v[j];
              if (dist < bd2) { bd2 = dist; bk2 = k; }
            }
          }
        }
        rd[(((i << 7) + pg) << 3) + kg] = bd2;
        rk[(((i << 7) + pg) << 3) + kg] = bk2;
      }
      __syncthreads();
      if (tid < 256) {
        const int lane = tid & 63, wv = tid >> 6;
        float bd = INF_F; int bk = KMAX;
        #pragma unroll
        for (int g = 0; g < 8; ++g) {   // ascending k-groups: ties keep lower k
          float dv = rd[(tid << 3) + g]; int kv = rk[(tid << 3) + g];
          if (dv < bd || (dv == bd && kv < bk)) { bd = dv; bk = kv; }
        }
        const bool far = bd > LAMBDA_F;
        const int zf = (far && (K < KMAX)) ? Kc : bk;
        zL[tid] = zf;
        atomicAdd(&lcnt[zf], 1);
        const float x2p = x2[pbase + tid];
        double a = (double)bd;
        double f = far ? (double)bd : 0.0;
        double xf = far ? (double)x2p : 0.0;
        unsigned long long bal = __ballot(far);
        int fc = __popcll(bal);
        #pragma unroll
        for (int m = 1; m < 64; m <<= 1) {
          a += __shfl_xor(a, m); f += __shfl_xor(f, m); xf += __shfl_xor(xf, m);
        }
        if (lane == 0) { wred[wv] = a; wred[4 + wv] = f; wred[8 + wv] = xf; wfc[wv] = fc; }
      }
      __syncthreads();
      if (tid == 0) {
        unsafeAtomicAdd(&sc->s_all[slot],  wred[0] + wred[1] + wred[2] + wred[3]);
        unsafeAtomicAdd(&sc->s_far[slot],  wred[4] + wred[5] + wred[6] + wred[7]);
        unsafeAtomicAdd(&sc->sx2far[slot], wred[8] + wred[9] + wred[10] + wred[11]);
        atomicAdd(&sc->farcnt[slot], wfc[0] + wfc[1] + wfc[2] + wfc[3]);
      }
      if (tid < 64) {
        int c = lcnt[tid];
        if (c > 0) atomicAdd(&sc->counts[slot][tid], c);
      }
    }

    // ---- Phase D: segment sums for the block's own 256 points (no barrier) ----
    {
      float* accS = smem;               // 64 x 256 floats = 64 KB
      const int pg4 = tid >> 8, dl = tid & 255;
      for (int c = 0; c < 4; ++c) {
        #pragma unroll
        for (int r = 0; r < 16; ++r) accS[(r << 10) + tid] = 0.f;
        __syncthreads();
        const float* xp = X + ((size_t)pbase << 10) + (c << 8) + dl;
        for (int i0 = 0; i0 < 64; i0 += 16) {
          float v[16]; int zi[16];
          #pragma unroll
          for (int u = 0; u < 16; ++u) {
            int p = (pg4 << 6) + i0 + u;
            v[u] = xp[(size_t)p << 10];
            zi[u] = zL[p];
          }
          #pragma unroll
          for (int u = 0; u < 16; ++u) atomicAdd(&accS[(zi[u] << 8) + dl], v[u]);
        }
        __syncthreads();
        for (int k = pg4; k < KMAX; k += 4)
          if (lcnt[k] > 0)
            unsafeAtomicAdd(&sums[(k << 10) + (c << 8) + dl],
                            (double)accS[(k << 8) + dl]);
        __syncthreads();
      }
    }
    gbar(bcnt, bgen);

    // ---- Phase E: centroid means + m2; block Kc does obj/convergence ----
    if (b < KMAX) {
      double* w = wred;
      const int k = b;
      if (tid < 256) {
        const int lane = tid & 63, wv = tid >> 6;
        const int c = sc->counts[slot][k];
        const double inv = (c > 0) ? 1.0 / (double)c : 0.0;
        double ss = 0.0;
        #pragma unroll
        for (int r = 0; r < 4; ++r) {
          int d = (r << 8) + tid;
          float m = mu[(k << 10) + d];
          if (c > 0) m = (float)(sums[(k << 10) + d] * inv);
          mu[(k << 10) + d] = m;
          sums[(k << 10) + d] = 0.0;
          ss += (double)m * (double)m;
        }
        #pragma unroll
        for (int mk = 1; mk < 64; mk <<= 1) ss += __shfl_xor(ss, mk);
        if (lane == 0) w[wv] = ss;
      }
      __syncthreads();
      if (tid == 0) {
        float m2k = (float)(w[0] + w[1] + w[2] + w[3]);
        m2f[k] = m2k;
        if (k == Kc) {
          #pragma unroll
          for (int q = 0; q < 64; ++q) sc->counts[slot ^ 1][q] = 0;
          sc->s_all[slot ^ 1] = 0.0; sc->s_far[slot ^ 1] = 0.0;
          sc->sx2far[slot ^ 1] = 0.0; sc->farcnt[slot ^ 1] = 0;
          int farc = sc->farcnt[slot];
          int create = (farc > 0 && K < KMAX) ? 1 : 0;
          int Knew = K + create;
          double obj;
          if (create)
            obj = (sc->s_all[slot] - sc->s_far[slot]) +
                  (sc->sx2far[slot] - (double)farc * (double)m2k);
          else
            obj = sc->s_all[slot];
          obj += 1000.0 * (double)Knew;
          int conv = (sc->it > 0) && (fabs(obj - sc->prev_obj) < 1e-3 * obj);
          sc->done = conv;
          sc->prev_obj = obj;
          sc->K = Knew;
          sc->it = sc->it + 1;
        }
      }
    }
    gbar(bcnt, bgen);
  }
}

// ---------------- host ----------------

extern "C" void kernel_launch(void* const* d_in, const int* in_sizes, int n_in,
                              void* d_out, int out_size, void* d_ws, size_t ws_size,
                              hipStream_t stream) {
  const float* X = (const float*)d_in[0];
  float* mu = (float*)d_out;                   // 64 x 1024 fp32 output
  char* ws = (char*)d_ws;
  float*  x2    = (float*)(ws + 0);            // 256 KB (fully written by kInitF)
  double* sums  = (double*)(ws + 262144);      // 512 KB  -- zeroed below
  double* musum = (double*)(ws + 786432);      // 8 KB    -- zeroed below
  Scal*   sc    = (Scal*)(ws + 794624);        // 1 KB    -- zeroed (K set by kMu0)
  int*    bar   = (int*)(ws + 795648);         // 256 B   -- zeroed below
  float*  m2f   = (float*)(ws + 795904);       // 256 B (fully written by kMu0)

  hipMemsetAsync(ws + 262144, 0, 533760, stream);
  kInitF<<<2048, 256, 0, stream>>>(X, x2, musum);
  kMu0<<<KMAX, 256, 0, stream>>>(musum, mu, m2f, sc);
  kLoop<<<GRID, 1024, 0, stream>>>(X, mu, x2, sums, m2f, sc, bar);
}